// Round 8
// baseline (69.865 us; speedup 1.0000x reference)
//
#include <hip/hip_runtime.h>
#include <hip/hip_bf16.h>

#define DIM 64
#define CAPX 128  // entries/row: max degree over 100k Poisson(32) rows ~65;
                  // 128 gives a huge safety margin against truncation
#define SBITS_WORDS 3200  // covers nItems <= 102400 (12.8 KB LDS)

typedef __attribute__((ext_vector_type(8))) short short8;
typedef __attribute__((ext_vector_type(4))) float f32x4;

__device__ __forceinline__ unsigned short f2bf(float f) {
  unsigned int u = __float_as_uint(f);
  u = (u + 0x7FFFu + ((u >> 16) & 1u)) >> 16;  // RNE; inputs are tame (no NaN)
  return (unsigned short)u;
}
__device__ __forceinline__ float bf2f(unsigned short h) {
  return __uint_as_float(((unsigned)h) << 16);
}

// Padding: one 64B cache line per reduction counter (R13 lesson).
#define SF_STRIDE 8   // sum_fixed: 8 ULL = 64B per shard
#define RD_STRIDE 16  // row_done: 16 int = 64B per row counter

// entry pack: col in bits [0,17), val*2^20 (<2^15) in bits [17,32)
#define VSCALE 1048576.0f
#define VINV (1.0f / 1048576.0f)

// ---------------------------------------------------------------------------
// prep v3: ONLY zeroing (selected rows' single count + reduction scratch).
// ---------------------------------------------------------------------------
__global__ void prep_kernel(const int* __restrict__ idx,
                            const int* __restrict__ ipos,
                            const int* __restrict__ ineg, int Bn,
                            int* __restrict__ counts,
                            unsigned long long* __restrict__ sum_fixed,
                            int* __restrict__ row_done, int* __restrict__ gdone,
                            int nrows) {
  int t = blockIdx.x * blockDim.x + threadIdx.x;
  if (t < 3 * Bn) {
    int r = (t < Bn) ? idx[t] : (t < 2 * Bn ? ipos[t - Bn] : ineg[t - 2 * Bn]);
    counts[r] = 0;
    if (t < nrows * SF_STRIDE) sum_fixed[t] = 0ULL;
    if (t < nrows * RD_STRIDE) row_done[t] = 0;
    if (t == 0) *gdone = 0;
  }
}

// ---------------------------------------------------------------------------
// scatter: per-block LDS bitmap filter, then one 8-edge pass. Selected edges
// append a PACKED 4B entry (col | val-fixed-point) to the row's SINGLE list
// (R6 proved bucket XCD-locality isn't load-bearing; one fat list minimizes
// accum's Poisson padding). ~32 atomics per row counter, parallel over ~12k
// rows — contention negligible. Correctness independent of block->XCD map.
// ---------------------------------------------------------------------------
__global__ __launch_bounds__(1024) void scatter3_kernel(
    const int4* __restrict__ er4, const int4* __restrict__ ec4,
    const float4* __restrict__ ev4, const int4* __restrict__ idx4,
    const int4* __restrict__ ipos4, const int4* __restrict__ ineg4, int Bn4,
    int* __restrict__ counts, unsigned* __restrict__ lists, int E8, int E) {
  __shared__ unsigned sbits[SBITS_WORDS];
  for (int i = threadIdx.x; i < SBITS_WORDS; i += 1024) sbits[i] = 0u;
  __syncthreads();
  for (int i = threadIdx.x; i < Bn4; i += 1024) {
    int4 a = idx4[i];
    int4 b = ipos4[i];
    int4 c = ineg4[i];
    atomicOr(&sbits[((unsigned)a.x) >> 5], 1u << (a.x & 31));
    atomicOr(&sbits[((unsigned)a.y) >> 5], 1u << (a.y & 31));
    atomicOr(&sbits[((unsigned)a.z) >> 5], 1u << (a.z & 31));
    atomicOr(&sbits[((unsigned)a.w) >> 5], 1u << (a.w & 31));
    atomicOr(&sbits[((unsigned)b.x) >> 5], 1u << (b.x & 31));
    atomicOr(&sbits[((unsigned)b.y) >> 5], 1u << (b.y & 31));
    atomicOr(&sbits[((unsigned)b.z) >> 5], 1u << (b.z & 31));
    atomicOr(&sbits[((unsigned)b.w) >> 5], 1u << (b.w & 31));
    atomicOr(&sbits[((unsigned)c.x) >> 5], 1u << (c.x & 31));
    atomicOr(&sbits[((unsigned)c.y) >> 5], 1u << (c.y & 31));
    atomicOr(&sbits[((unsigned)c.z) >> 5], 1u << (c.z & 31));
    atomicOr(&sbits[((unsigned)c.w) >> 5], 1u << (c.w & 31));
  }
  __syncthreads();

  int i = blockIdx.x * blockDim.x + threadIdx.x;
  if (i < E8) {
    int4 r0 = er4[2 * i];
    int4 r1 = er4[2 * i + 1];
    int rr[8] = {r0.x, r0.y, r0.z, r0.w, r1.x, r1.y, r1.z, r1.w};
    unsigned m[8];
    unsigned any = 0;
#pragma unroll
    for (int k = 0; k < 8; ++k) {
      m[k] = (sbits[((unsigned)rr[k]) >> 5] >> (rr[k] & 31)) & 1u;
      any |= m[k];
    }
    if (any) {  // lazy: col/val streams touched only for ~63% of groups
      int4 c0 = ec4[2 * i];
      int4 c1 = ec4[2 * i + 1];
      float4 v0 = ev4[2 * i];
      float4 v1 = ev4[2 * i + 1];
      int cc[8] = {c0.x, c0.y, c0.z, c0.w, c1.x, c1.y, c1.z, c1.w};
      float vv[8] = {v0.x, v0.y, v0.z, v0.w, v1.x, v1.y, v1.z, v1.w};
#pragma unroll
      for (int k = 0; k < 8; ++k) {
        if (m[k]) {
          int r = rr[k];
          int p = atomicAdd(&counts[r], 1);
          if (p < CAPX) {
            unsigned pv = __float2uint_rn(vv[k] * VSCALE);  // < 2^15
            lists[(size_t)r * CAPX + p] = (pv << 17) | (unsigned)cc[k];
          }
        }
      }
    }
  }
  // tail (E % 8 != 0) — first global thread; no-op at this problem size
  if (i == 0) {
    const int* er = (const int*)er4;
    const int* ec = (const int*)ec4;
    const float* ev = (const float*)ev4;
    for (int e = (E >> 3) << 3; e < E; ++e) {
      int r = er[e];
      if ((sbits[((unsigned)r) >> 5] >> (r & 31)) & 1u) {
        int p = atomicAdd(&counts[r], 1);
        if (p < CAPX) {
          unsigned pv = __float2uint_rn(ev[e] * VSCALE);
          lists[(size_t)r * CAPX + p] = (pv << 17) | (unsigned)ec[e];
        }
      }
    }
  }
}

// ---------------------------------------------------------------------------
// fused accumulate + build, v9 (single fat list; FUSED B-task dual gather):
//  * A-tasks: one list, rounds = ceil(n/8), 2 x uint4 entry loads + 8
//    independent feat loads per round (proven MLP>=8 shape).
//  * B-tasks: pos+neg lists interleaved in ONE round loop, rounds =
//    ceil(max(np,nn)/8), 4 x uint4 entry loads + 16 independent feat loads
//    per round. Serial dependent-round depth on B-waves HALVES (~8.9 -> ~5)
//    for only ~+8 padded slots/B-gather (E[max] of two Poisson(32) chunks).
//    R2's fusion failure was the 16-stream jmax structure (+25% slots); the
//    single-list version pays ~5% total slots for 2x shorter B critical path.
//  * Per-list accumulation/scaling kept byte-identical to v8 (gp and gn
//    finished separately, then subtracted) — same rounding behavior.
// ---------------------------------------------------------------------------
__global__ __launch_bounds__(256, 4) void accum_build_kernel(
    const int* __restrict__ counts, const unsigned* __restrict__ lists,
    const float* __restrict__ feat, const int* __restrict__ idx,
    const int* __restrict__ ipos, const int* __restrict__ ineg,
    unsigned short* __restrict__ A, unsigned short* __restrict__ Bm, int Bn) {
  int wv = (blockIdx.x * blockDim.x + threadIdx.x) >> 6;
  int lane = threadIdx.x & 63;

  auto gather = [&](int r) -> float {
    int n = counts[r];
    n = n > CAPX ? CAPX : n;
    const uint4* base4 = (const uint4*)(lists + (size_t)r * CAPX);
    float acc0 = 0.0f, acc1 = 0.0f;
    int rounds = (n + 7) >> 3;
    for (int c = 0; c < rounds; ++c) {  // wave-uniform trip count
      uint4 ea = base4[2 * c];
      uint4 eb = base4[2 * c + 1];
      unsigned sa[4] = {ea.x, ea.y, ea.z, ea.w};
      unsigned sb[4] = {eb.x, eb.y, eb.z, eb.w};
      int j0 = c << 3;
#pragma unroll
      for (int k = 0; k < 4; ++k) {
        unsigned e = (j0 + k < n) ? sa[k] : 0u;  // masked -> row 0 (L2-hot)
        float f = feat[((size_t)(e & 0x1FFFFu)) * DIM + lane];
        acc0 = fmaf((float)(e >> 17), f, acc0);
      }
#pragma unroll
      for (int k = 0; k < 4; ++k) {
        unsigned e = (j0 + 4 + k < n) ? sb[k] : 0u;
        float f = feat[((size_t)(e & 0x1FFFFu)) * DIM + lane];
        acc1 = fmaf((float)(e >> 17), f, acc1);
      }
    }
    return 0.5f * ((acc0 + acc1) * VINV + feat[(size_t)r * DIM + lane]);
  };

  auto gather2 = [&](int rp, int rn) -> float {
    int np = counts[rp];
    int nn = counts[rn];
    np = np > CAPX ? CAPX : np;
    nn = nn > CAPX ? CAPX : nn;
    const uint4* bp4 = (const uint4*)(lists + (size_t)rp * CAPX);
    const uint4* bn4 = (const uint4*)(lists + (size_t)rn * CAPX);
    float ap0 = 0.0f, ap1 = 0.0f, an0 = 0.0f, an1 = 0.0f;
    int mx = np > nn ? np : nn;
    int rounds = (mx + 7) >> 3;
    for (int c = 0; c < rounds; ++c) {  // wave-uniform trip count
      uint4 pa = bp4[2 * c];
      uint4 pb = bp4[2 * c + 1];
      uint4 qa = bn4[2 * c];
      uint4 qb = bn4[2 * c + 1];
      unsigned sp0[4] = {pa.x, pa.y, pa.z, pa.w};
      unsigned sp1[4] = {pb.x, pb.y, pb.z, pb.w};
      unsigned sn0[4] = {qa.x, qa.y, qa.z, qa.w};
      unsigned sn1[4] = {qb.x, qb.y, qb.z, qb.w};
      int j0 = c << 3;
#pragma unroll
      for (int k = 0; k < 4; ++k) {
        unsigned e = (j0 + k < np) ? sp0[k] : 0u;
        float f = feat[((size_t)(e & 0x1FFFFu)) * DIM + lane];
        ap0 = fmaf((float)(e >> 17), f, ap0);
      }
#pragma unroll
      for (int k = 0; k < 4; ++k) {
        unsigned e = (j0 + 4 + k < np) ? sp1[k] : 0u;
        float f = feat[((size_t)(e & 0x1FFFFu)) * DIM + lane];
        ap1 = fmaf((float)(e >> 17), f, ap1);
      }
#pragma unroll
      for (int k = 0; k < 4; ++k) {
        unsigned e = (j0 + k < nn) ? sn0[k] : 0u;
        float f = feat[((size_t)(e & 0x1FFFFu)) * DIM + lane];
        an0 = fmaf((float)(e >> 17), f, an0);
      }
#pragma unroll
      for (int k = 0; k < 4; ++k) {
        unsigned e = (j0 + 4 + k < nn) ? sn1[k] : 0u;
        float f = feat[((size_t)(e & 0x1FFFFu)) * DIM + lane];
        an1 = fmaf((float)(e >> 17), f, an1);
      }
    }
    float gp = 0.5f * ((ap0 + ap1) * VINV + feat[(size_t)rp * DIM + lane]);
    float gn = 0.5f * ((an0 + an1) * VINV + feat[(size_t)rn * DIM + lane]);
    return gp - gn;
  };

  if (wv < Bn) {
    int b = wv;
    float v = gather(idx[b]);
    A[((size_t)((b >> 4) * 8 + (lane >> 3))) * 128 + (b & 15) * 8 + (lane & 7)] =
        f2bf(v);
  } else if (wv < 2 * Bn) {
    int j = wv - Bn;
    float v = gather2(ipos[j], ineg[j]);
    Bm[((size_t)((j >> 4) * 8 + (lane >> 3))) * 128 + (j & 15) * 8 + (lane & 7)] =
        f2bf(v);
  }
}

// ---------------------------------------------------------------------------
// GEMM + loss via bf16 MFMA with fused, line-padded, sharded reduction
// (proven in R14). All-integer atomics -> deterministic.
// ---------------------------------------------------------------------------
__global__ __launch_bounds__(256) void gemm_loss_kernel(
    const short8* __restrict__ A, const short8* __restrict__ Bm,
    unsigned long long* __restrict__ sum_fixed, int* __restrict__ row_done,
    int* __restrict__ gdone, float* __restrict__ out, double inv) {
  int t = threadIdx.x;
  int lane = t & 63;
  int w = t >> 6;
  int wr = w >> 1;
  int wc = w & 1;
  int frow = lane & 15;
  int hi = lane >> 4;

  int ablk = blockIdx.y * 8 + wr * 4;
  int bblk = blockIdx.x * 8 + wc * 4;

  f32x4 acc[4][4];
#pragma unroll
  for (int m = 0; m < 4; ++m)
#pragma unroll
    for (int n = 0; n < 4; ++n) acc[m][n] = (f32x4){0.f, 0.f, 0.f, 0.f};

#pragma unroll
  for (int kk = 0; kk < 2; ++kk) {
    short8 a[4], b[4];
#pragma unroll
    for (int m = 0; m < 4; ++m)
      a[m] = A[((ablk + m) * 8 + kk * 4 + hi) * 16 + frow];
#pragma unroll
    for (int n = 0; n < 4; ++n)
      b[n] = Bm[((bblk + n) * 8 + kk * 4 + hi) * 16 + frow];
#pragma unroll
    for (int m = 0; m < 4; ++m)
#pragma unroll
      for (int n = 0; n < 4; ++n)
        acc[m][n] = __builtin_amdgcn_mfma_f32_16x16x32_bf16(a[m], b[n],
                                                            acc[m][n], 0, 0, 0);
  }

  float local = 0.0f;
#pragma unroll
  for (int m = 0; m < 4; ++m)
#pragma unroll
    for (int n = 0; n < 4; ++n)
#pragma unroll
      for (int i = 0; i < 4; ++i) {
        float z = -acc[m][n][i];
        float az = fabsf(z);
        local += fmaxf(z, 0.0f) + __logf(1.0f + __expf(-az));
      }
#pragma unroll
  for (int off = 32; off > 0; off >>= 1) local += __shfl_down(local, off, 64);

  __shared__ float red[4];
  if (lane == 0) red[w] = local;
  __syncthreads();

  if (w == 0) {
    int last = 0;
    if (lane == 0) {
      double bs = (double)red[0] + red[1] + red[2] + red[3];
      long long f = (long long)llrint(bs * 1048576.0);
      unsigned long long old =
          atomicAdd(&sum_fixed[blockIdx.y * SF_STRIDE], (unsigned long long)f);
      int inc = 1 | (int)(old >> 63);  // == 1, runtime-opaque (orders the add)
      int pos = atomicAdd(&row_done[blockIdx.y * RD_STRIDE], inc);
      if (pos == (int)gridDim.x - 1) {
        int g = atomicAdd(gdone, 1);
        last = (g == (int)gridDim.y - 1);
      }
    }
    last = __shfl(last, 0, 64);
    if (last) {
      long long part = 0;
      if (lane < (int)gridDim.y)
        part = (long long)atomicAdd(&sum_fixed[lane * SF_STRIDE], 0ULL);
#pragma unroll
      for (int off = 32; off > 0; off >>= 1)
        part += __shfl_down(part, off, 64);
      if (lane == 0)
        out[0] = (float)((double)part * inv * (1.0 / 1048576.0));
    }
  }
}

// ---------------------------------------------------------------------------
extern "C" void kernel_launch(void* const* d_in, const int* in_sizes, int n_in,
                              void* d_out, int out_size, void* d_ws,
                              size_t ws_size, hipStream_t stream) {
  const float* feat = (const float*)d_in[0];
  const float* evals = (const float*)d_in[1];
  const int* erows = (const int*)d_in[2];
  const int* ecols = (const int*)d_in[3];
  const int* idx = (const int*)d_in[4];
  const int* ipos = (const int*)d_in[5];
  const int* ineg = (const int*)d_in[6];
  float* out = (float*)d_out;

  int nItems = in_sizes[0] / DIM;
  int E = in_sizes[1];
  int Bn = in_sizes[4];

  // workspace bump allocator (256B aligned); ~53 MB of ~256 MiB ws.
  char* w = (char*)d_ws;
  size_t off = 0;
  auto alloc = [&](size_t bytes) -> void* {
    void* p = w + off;
    off += (bytes + 255) & ~(size_t)255;
    return p;
  };
  int* counts = (int*)alloc((size_t)nItems * 4);
  unsigned* lists = (unsigned*)alloc((size_t)nItems * CAPX * 4 + 2048);
  unsigned short* Amat = (unsigned short*)alloc((size_t)Bn * DIM * 2);
  unsigned short* Bmat = (unsigned short*)alloc((size_t)Bn * DIM * 2);
  int gx = Bn / 128;  // 32
  unsigned long long* sum_fixed =
      (unsigned long long*)alloc((size_t)gx * SF_STRIDE * 8);
  int* row_done = (int*)alloc((size_t)gx * RD_STRIDE * 4);
  int* gdone = (int*)alloc(64);

  prep_kernel<<<(3 * Bn + 255) / 256, 256, 0, stream>>>(
      idx, ipos, ineg, Bn, counts, sum_fixed, row_done, gdone, gx);

  int E8 = E / 8;
  scatter3_kernel<<<512, 1024, 0, stream>>>(
      (const int4*)erows, (const int4*)ecols, (const float4*)evals,
      (const int4*)idx, (const int4*)ipos, (const int4*)ineg, Bn / 4, counts,
      lists, E8, E);

  int nWaves = 2 * Bn;  // 4096 A-tasks + 4096 fused-B-tasks
  accum_build_kernel<<<(nWaves * 64 + 255) / 256, 256, 0, stream>>>(
      counts, lists, feat, idx, ipos, ineg, Amat, Bmat, Bn);

  double inv = 1.0 / ((double)Bn * (double)Bn);
  gemm_loss_kernel<<<dim3(gx, gx), 256, 0, stream>>>(
      (const short8*)Amat, (const short8*)Bmat, sum_fixed, row_done, gdone,
      out, inv);
}

// Round 9
// 66.483 us; speedup vs baseline: 1.0509x; 1.0509x over previous
//
#include <hip/hip_runtime.h>
#include <hip/hip_bf16.h>

#define DIM 64
#define CAPX 128  // entries/row: max degree over 100k Poisson(32) rows ~65;
                  // 128 gives a huge safety margin against truncation
#define SBITS_WORDS 3200  // covers nItems <= 102400 (12.8 KB LDS)

typedef __attribute__((ext_vector_type(8))) short short8;
typedef __attribute__((ext_vector_type(4))) float f32x4;

__device__ __forceinline__ unsigned short f2bf(float f) {
  unsigned int u = __float_as_uint(f);
  u = (u + 0x7FFFu + ((u >> 16) & 1u)) >> 16;  // RNE; inputs are tame (no NaN)
  return (unsigned short)u;
}
__device__ __forceinline__ float bf2f(unsigned short h) {
  return __uint_as_float(((unsigned)h) << 16);
}

// Padding: one 64B cache line per reduction counter (R13 lesson).
#define SF_STRIDE 8   // sum_fixed: 8 ULL = 64B per shard
#define RD_STRIDE 16  // row_done: 16 int = 64B per row counter

// entry pack: col in bits [0,17), val*2^20 (<2^15) in bits [17,32)
#define VSCALE 1048576.0f
#define VINV (1.0f / 1048576.0f)

// ---------------------------------------------------------------------------
// prep v3: ONLY zeroing (selected rows' single count + reduction scratch).
// ---------------------------------------------------------------------------
__global__ void prep_kernel(const int* __restrict__ idx,
                            const int* __restrict__ ipos,
                            const int* __restrict__ ineg, int Bn,
                            int* __restrict__ counts,
                            unsigned long long* __restrict__ sum_fixed,
                            int* __restrict__ row_done, int* __restrict__ gdone,
                            int nrows) {
  int t = blockIdx.x * blockDim.x + threadIdx.x;
  if (t < 3 * Bn) {
    int r = (t < Bn) ? idx[t] : (t < 2 * Bn ? ipos[t - Bn] : ineg[t - 2 * Bn]);
    counts[r] = 0;
    if (t < nrows * SF_STRIDE) sum_fixed[t] = 0ULL;
    if (t < nrows * RD_STRIDE) row_done[t] = 0;
    if (t == 0) *gdone = 0;
  }
}

// ---------------------------------------------------------------------------
// scatter: per-block LDS bitmap filter, then one 8-edge pass. Selected edges
// append a PACKED 4B entry (col | val-fixed-point) to the row's SINGLE list
// (R6 proved bucket XCD-locality isn't load-bearing; one fat list minimizes
// accum's Poisson padding). ~32 atomics per row counter, parallel over ~12k
// rows — contention negligible. Correctness independent of block->XCD map.
// ---------------------------------------------------------------------------
__global__ __launch_bounds__(1024) void scatter3_kernel(
    const int4* __restrict__ er4, const int4* __restrict__ ec4,
    const float4* __restrict__ ev4, const int4* __restrict__ idx4,
    const int4* __restrict__ ipos4, const int4* __restrict__ ineg4, int Bn4,
    int* __restrict__ counts, unsigned* __restrict__ lists, int E8, int E) {
  __shared__ unsigned sbits[SBITS_WORDS];
  for (int i = threadIdx.x; i < SBITS_WORDS; i += 1024) sbits[i] = 0u;
  __syncthreads();
  for (int i = threadIdx.x; i < Bn4; i += 1024) {
    int4 a = idx4[i];
    int4 b = ipos4[i];
    int4 c = ineg4[i];
    atomicOr(&sbits[((unsigned)a.x) >> 5], 1u << (a.x & 31));
    atomicOr(&sbits[((unsigned)a.y) >> 5], 1u << (a.y & 31));
    atomicOr(&sbits[((unsigned)a.z) >> 5], 1u << (a.z & 31));
    atomicOr(&sbits[((unsigned)a.w) >> 5], 1u << (a.w & 31));
    atomicOr(&sbits[((unsigned)b.x) >> 5], 1u << (b.x & 31));
    atomicOr(&sbits[((unsigned)b.y) >> 5], 1u << (b.y & 31));
    atomicOr(&sbits[((unsigned)b.z) >> 5], 1u << (b.z & 31));
    atomicOr(&sbits[((unsigned)b.w) >> 5], 1u << (b.w & 31));
    atomicOr(&sbits[((unsigned)c.x) >> 5], 1u << (c.x & 31));
    atomicOr(&sbits[((unsigned)c.y) >> 5], 1u << (c.y & 31));
    atomicOr(&sbits[((unsigned)c.z) >> 5], 1u << (c.z & 31));
    atomicOr(&sbits[((unsigned)c.w) >> 5], 1u << (c.w & 31));
  }
  __syncthreads();

  int i = blockIdx.x * blockDim.x + threadIdx.x;
  if (i < E8) {
    int4 r0 = er4[2 * i];
    int4 r1 = er4[2 * i + 1];
    int rr[8] = {r0.x, r0.y, r0.z, r0.w, r1.x, r1.y, r1.z, r1.w};
    unsigned m[8];
    unsigned any = 0;
#pragma unroll
    for (int k = 0; k < 8; ++k) {
      m[k] = (sbits[((unsigned)rr[k]) >> 5] >> (rr[k] & 31)) & 1u;
      any |= m[k];
    }
    if (any) {  // lazy: col/val streams touched only for ~63% of groups
      int4 c0 = ec4[2 * i];
      int4 c1 = ec4[2 * i + 1];
      float4 v0 = ev4[2 * i];
      float4 v1 = ev4[2 * i + 1];
      int cc[8] = {c0.x, c0.y, c0.z, c0.w, c1.x, c1.y, c1.z, c1.w};
      float vv[8] = {v0.x, v0.y, v0.z, v0.w, v1.x, v1.y, v1.z, v1.w};
#pragma unroll
      for (int k = 0; k < 8; ++k) {
        if (m[k]) {
          int r = rr[k];
          int p = atomicAdd(&counts[r], 1);
          if (p < CAPX) {
            unsigned pv = __float2uint_rn(vv[k] * VSCALE);  // < 2^15
            lists[(size_t)r * CAPX + p] = (pv << 17) | (unsigned)cc[k];
          }
        }
      }
    }
  }
  // tail (E % 8 != 0) — first global thread; no-op at this problem size
  if (i == 0) {
    const int* er = (const int*)er4;
    const int* ec = (const int*)ec4;
    const float* ev = (const float*)ev4;
    for (int e = (E >> 3) << 3; e < E; ++e) {
      int r = er[e];
      if ((sbits[((unsigned)r) >> 5] >> (r & 31)) & 1u) {
        int p = atomicAdd(&counts[r], 1);
        if (p < CAPX) {
          unsigned pv = __float2uint_rn(ev[e] * VSCALE);
          lists[(size_t)r * CAPX + p] = (pv << 17) | (unsigned)ec[e];
        }
      }
    }
  }
}

// ---------------------------------------------------------------------------
// fused accumulate + build, v10 = R7's proven v8 gather + occupancy push:
//  * single fat list, rounds = ceil(n/8), 2 x uint4 entry loads + 8
//    independent feat loads per round (proven MLP=8 shape; R8's 16-stream
//    fusion regressed on register pressure — reverted).
//  * __launch_bounds__(256, 8): live state ~40-50 VGPR fits the <=64 bin;
//    8 waves/EU doubles resident waves (all 2048 blocks co-resident) to
//    cover the ~3.5us latency gap above accum's ~9us L3-traffic floor.
// ---------------------------------------------------------------------------
__global__ __launch_bounds__(256, 8) void accum_build_kernel(
    const int* __restrict__ counts, const unsigned* __restrict__ lists,
    const float* __restrict__ feat, const int* __restrict__ idx,
    const int* __restrict__ ipos, const int* __restrict__ ineg,
    unsigned short* __restrict__ A, unsigned short* __restrict__ Bm, int Bn) {
  int wv = (blockIdx.x * blockDim.x + threadIdx.x) >> 6;
  int lane = threadIdx.x & 63;

  auto gather = [&](int r) -> float {
    int n = counts[r];
    n = n > CAPX ? CAPX : n;
    const uint4* base4 = (const uint4*)(lists + (size_t)r * CAPX);
    float acc0 = 0.0f, acc1 = 0.0f;
    int rounds = (n + 7) >> 3;
    for (int c = 0; c < rounds; ++c) {  // wave-uniform trip count
      uint4 ea = base4[2 * c];
      uint4 eb = base4[2 * c + 1];
      unsigned sa[4] = {ea.x, ea.y, ea.z, ea.w};
      unsigned sb[4] = {eb.x, eb.y, eb.z, eb.w};
      int j0 = c << 3;
#pragma unroll
      for (int k = 0; k < 4; ++k) {
        unsigned e = (j0 + k < n) ? sa[k] : 0u;  // masked -> row 0 (L2-hot)
        float f = feat[((size_t)(e & 0x1FFFFu)) * DIM + lane];
        acc0 = fmaf((float)(e >> 17), f, acc0);
      }
#pragma unroll
      for (int k = 0; k < 4; ++k) {
        unsigned e = (j0 + 4 + k < n) ? sb[k] : 0u;
        float f = feat[((size_t)(e & 0x1FFFFu)) * DIM + lane];
        acc1 = fmaf((float)(e >> 17), f, acc1);
      }
    }
    return 0.5f * ((acc0 + acc1) * VINV + feat[(size_t)r * DIM + lane]);
  };

  if (wv < Bn) {
    int b = wv;
    float v = gather(idx[b]);
    A[((size_t)((b >> 4) * 8 + (lane >> 3))) * 128 + (b & 15) * 8 + (lane & 7)] =
        f2bf(v);
  } else if (wv < 2 * Bn) {
    int j = wv - Bn;
    float v = gather(ipos[j]) - gather(ineg[j]);
    Bm[((size_t)((j >> 4) * 8 + (lane >> 3))) * 128 + (j & 15) * 8 + (lane & 7)] =
        f2bf(v);
  }
}

// ---------------------------------------------------------------------------
// GEMM + loss via bf16 MFMA with fused, line-padded, sharded reduction
// (proven in R14). All-integer atomics -> deterministic.
// ---------------------------------------------------------------------------
__global__ __launch_bounds__(256) void gemm_loss_kernel(
    const short8* __restrict__ A, const short8* __restrict__ Bm,
    unsigned long long* __restrict__ sum_fixed, int* __restrict__ row_done,
    int* __restrict__ gdone, float* __restrict__ out, double inv) {
  int t = threadIdx.x;
  int lane = t & 63;
  int w = t >> 6;
  int wr = w >> 1;
  int wc = w & 1;
  int frow = lane & 15;
  int hi = lane >> 4;

  int ablk = blockIdx.y * 8 + wr * 4;
  int bblk = blockIdx.x * 8 + wc * 4;

  f32x4 acc[4][4];
#pragma unroll
  for (int m = 0; m < 4; ++m)
#pragma unroll
    for (int n = 0; n < 4; ++n) acc[m][n] = (f32x4){0.f, 0.f, 0.f, 0.f};

#pragma unroll
  for (int kk = 0; kk < 2; ++kk) {
    short8 a[4], b[4];
#pragma unroll
    for (int m = 0; m < 4; ++m)
      a[m] = A[((ablk + m) * 8 + kk * 4 + hi) * 16 + frow];
#pragma unroll
    for (int n = 0; n < 4; ++n)
      b[n] = Bm[((bblk + n) * 8 + kk * 4 + hi) * 16 + frow];
#pragma unroll
    for (int m = 0; m < 4; ++m)
#pragma unroll
      for (int n = 0; n < 4; ++n)
        acc[m][n] = __builtin_amdgcn_mfma_f32_16x16x32_bf16(a[m], b[n],
                                                            acc[m][n], 0, 0, 0);
  }

  float local = 0.0f;
#pragma unroll
  for (int m = 0; m < 4; ++m)
#pragma unroll
    for (int n = 0; n < 4; ++n)
#pragma unroll
      for (int i = 0; i < 4; ++i) {
        float z = -acc[m][n][i];
        float az = fabsf(z);
        local += fmaxf(z, 0.0f) + __logf(1.0f + __expf(-az));
      }
#pragma unroll
  for (int off = 32; off > 0; off >>= 1) local += __shfl_down(local, off, 64);

  __shared__ float red[4];
  if (lane == 0) red[w] = local;
  __syncthreads();

  if (w == 0) {
    int last = 0;
    if (lane == 0) {
      double bs = (double)red[0] + red[1] + red[2] + red[3];
      long long f = (long long)llrint(bs * 1048576.0);
      unsigned long long old =
          atomicAdd(&sum_fixed[blockIdx.y * SF_STRIDE], (unsigned long long)f);
      int inc = 1 | (int)(old >> 63);  // == 1, runtime-opaque (orders the add)
      int pos = atomicAdd(&row_done[blockIdx.y * RD_STRIDE], inc);
      if (pos == (int)gridDim.x - 1) {
        int g = atomicAdd(gdone, 1);
        last = (g == (int)gridDim.y - 1);
      }
    }
    last = __shfl(last, 0, 64);
    if (last) {
      long long part = 0;
      if (lane < (int)gridDim.y)
        part = (long long)atomicAdd(&sum_fixed[lane * SF_STRIDE], 0ULL);
#pragma unroll
      for (int off = 32; off > 0; off >>= 1)
        part += __shfl_down(part, off, 64);
      if (lane == 0)
        out[0] = (float)((double)part * inv * (1.0 / 1048576.0));
    }
  }
}

// ---------------------------------------------------------------------------
extern "C" void kernel_launch(void* const* d_in, const int* in_sizes, int n_in,
                              void* d_out, int out_size, void* d_ws,
                              size_t ws_size, hipStream_t stream) {
  const float* feat = (const float*)d_in[0];
  const float* evals = (const float*)d_in[1];
  const int* erows = (const int*)d_in[2];
  const int* ecols = (const int*)d_in[3];
  const int* idx = (const int*)d_in[4];
  const int* ipos = (const int*)d_in[5];
  const int* ineg = (const int*)d_in[6];
  float* out = (float*)d_out;

  int nItems = in_sizes[0] / DIM;
  int E = in_sizes[1];
  int Bn = in_sizes[4];

  // workspace bump allocator (256B aligned); ~53 MB of ~256 MiB ws.
  char* w = (char*)d_ws;
  size_t off = 0;
  auto alloc = [&](size_t bytes) -> void* {
    void* p = w + off;
    off += (bytes + 255) & ~(size_t)255;
    return p;
  };
  int* counts = (int*)alloc((size_t)nItems * 4);
  unsigned* lists = (unsigned*)alloc((size_t)nItems * CAPX * 4 + 2048);
  unsigned short* Amat = (unsigned short*)alloc((size_t)Bn * DIM * 2);
  unsigned short* Bmat = (unsigned short*)alloc((size_t)Bn * DIM * 2);
  int gx = Bn / 128;  // 32
  unsigned long long* sum_fixed =
      (unsigned long long*)alloc((size_t)gx * SF_STRIDE * 8);
  int* row_done = (int*)alloc((size_t)gx * RD_STRIDE * 4);
  int* gdone = (int*)alloc(64);

  prep_kernel<<<(3 * Bn + 255) / 256, 256, 0, stream>>>(
      idx, ipos, ineg, Bn, counts, sum_fixed, row_done, gdone, gx);

  int E8 = E / 8;
  scatter3_kernel<<<512, 1024, 0, stream>>>(
      (const int4*)erows, (const int4*)ecols, (const float4*)evals,
      (const int4*)idx, (const int4*)ipos, (const int4*)ineg, Bn / 4, counts,
      lists, E8, E);

  int nWaves = 2 * Bn;  // 4096 A-tasks + 4096 B-tasks
  accum_build_kernel<<<(nWaves * 64 + 255) / 256, 256, 0, stream>>>(
      counts, lists, feat, idx, ipos, ineg, Amat, Bmat, Bn);

  double inv = 1.0 / ((double)Bn * (double)Bn);
  gemm_loss_kernel<<<dim3(gx, gx), 256, 0, stream>>>(
      (const short8*)Amat, (const short8*)Bmat, sum_fixed, row_done, gdone,
      out, inv);
}

// Round 10
// 65.618 us; speedup vs baseline: 1.0647x; 1.0132x over previous
//
#include <hip/hip_runtime.h>
#include <hip/hip_bf16.h>

#define DIM 64
#define CAPX 128  // entries/row: max degree over 100k Poisson(32) rows ~65;
                  // 128 gives a huge safety margin against truncation
#define SBITS_WORDS 3200  // covers nItems <= 102400 (12.8 KB LDS)

typedef __attribute__((ext_vector_type(8))) short short8;
typedef __attribute__((ext_vector_type(4))) float f32x4;

__device__ __forceinline__ unsigned short f2bf(float f) {
  unsigned int u = __float_as_uint(f);
  u = (u + 0x7FFFu + ((u >> 16) & 1u)) >> 16;  // RNE; inputs are tame (no NaN)
  return (unsigned short)u;
}
__device__ __forceinline__ float bf2f(unsigned short h) {
  return __uint_as_float(((unsigned)h) << 16);
}

// Padding: one 64B cache line per reduction counter (R13 lesson).
#define SF_STRIDE 8   // sum_fixed: 8 ULL = 64B per shard
#define RD_STRIDE 16  // row_done: 16 int = 64B per row counter

// entry pack: col in bits [0,17), val*2^20 (<2^15) in bits [17,32)
#define VSCALE 1048576.0f
#define VINV (1.0f / 1048576.0f)

// ---------------------------------------------------------------------------
// prep v3: ONLY zeroing (selected rows' single count + reduction scratch).
// ---------------------------------------------------------------------------
__global__ void prep_kernel(const int* __restrict__ idx,
                            const int* __restrict__ ipos,
                            const int* __restrict__ ineg, int Bn,
                            int* __restrict__ counts,
                            unsigned long long* __restrict__ sum_fixed,
                            int* __restrict__ row_done, int* __restrict__ gdone,
                            int nrows) {
  int t = blockIdx.x * blockDim.x + threadIdx.x;
  if (t < 3 * Bn) {
    int r = (t < Bn) ? idx[t] : (t < 2 * Bn ? ipos[t - Bn] : ineg[t - 2 * Bn]);
    counts[r] = 0;
    if (t < nrows * SF_STRIDE) sum_fixed[t] = 0ULL;
    if (t < nrows * RD_STRIDE) row_done[t] = 0;
    if (t == 0) *gdone = 0;
  }
}

// ---------------------------------------------------------------------------
// scatter: per-block LDS bitmap filter, then one 8-edge pass. Selected edges
// append a PACKED 4B entry (col | val-fixed-point) to the row's SINGLE list
// (R6 proved bucket XCD-locality isn't load-bearing; one fat list minimizes
// accum's Poisson padding). ~32 atomics per row counter, parallel over ~12k
// rows — contention negligible. Correctness independent of block->XCD map.
// ---------------------------------------------------------------------------
__global__ __launch_bounds__(1024) void scatter3_kernel(
    const int4* __restrict__ er4, const int4* __restrict__ ec4,
    const float4* __restrict__ ev4, const int4* __restrict__ idx4,
    const int4* __restrict__ ipos4, const int4* __restrict__ ineg4, int Bn4,
    int* __restrict__ counts, unsigned* __restrict__ lists, int E8, int E) {
  __shared__ unsigned sbits[SBITS_WORDS];
  for (int i = threadIdx.x; i < SBITS_WORDS; i += 1024) sbits[i] = 0u;
  __syncthreads();
  for (int i = threadIdx.x; i < Bn4; i += 1024) {
    int4 a = idx4[i];
    int4 b = ipos4[i];
    int4 c = ineg4[i];
    atomicOr(&sbits[((unsigned)a.x) >> 5], 1u << (a.x & 31));
    atomicOr(&sbits[((unsigned)a.y) >> 5], 1u << (a.y & 31));
    atomicOr(&sbits[((unsigned)a.z) >> 5], 1u << (a.z & 31));
    atomicOr(&sbits[((unsigned)a.w) >> 5], 1u << (a.w & 31));
    atomicOr(&sbits[((unsigned)b.x) >> 5], 1u << (b.x & 31));
    atomicOr(&sbits[((unsigned)b.y) >> 5], 1u << (b.y & 31));
    atomicOr(&sbits[((unsigned)b.z) >> 5], 1u << (b.z & 31));
    atomicOr(&sbits[((unsigned)b.w) >> 5], 1u << (b.w & 31));
    atomicOr(&sbits[((unsigned)c.x) >> 5], 1u << (c.x & 31));
    atomicOr(&sbits[((unsigned)c.y) >> 5], 1u << (c.y & 31));
    atomicOr(&sbits[((unsigned)c.z) >> 5], 1u << (c.z & 31));
    atomicOr(&sbits[((unsigned)c.w) >> 5], 1u << (c.w & 31));
  }
  __syncthreads();

  int i = blockIdx.x * blockDim.x + threadIdx.x;
  if (i < E8) {
    int4 r0 = er4[2 * i];
    int4 r1 = er4[2 * i + 1];
    int rr[8] = {r0.x, r0.y, r0.z, r0.w, r1.x, r1.y, r1.z, r1.w};
    unsigned m[8];
    unsigned any = 0;
#pragma unroll
    for (int k = 0; k < 8; ++k) {
      m[k] = (sbits[((unsigned)rr[k]) >> 5] >> (rr[k] & 31)) & 1u;
      any |= m[k];
    }
    if (any) {  // lazy: col/val streams touched only for ~63% of groups
      int4 c0 = ec4[2 * i];
      int4 c1 = ec4[2 * i + 1];
      float4 v0 = ev4[2 * i];
      float4 v1 = ev4[2 * i + 1];
      int cc[8] = {c0.x, c0.y, c0.z, c0.w, c1.x, c1.y, c1.z, c1.w};
      float vv[8] = {v0.x, v0.y, v0.z, v0.w, v1.x, v1.y, v1.z, v1.w};
#pragma unroll
      for (int k = 0; k < 8; ++k) {
        if (m[k]) {
          int r = rr[k];
          int p = atomicAdd(&counts[r], 1);
          if (p < CAPX) {
            unsigned pv = __float2uint_rn(vv[k] * VSCALE);  // < 2^15
            lists[(size_t)r * CAPX + p] = (pv << 17) | (unsigned)cc[k];
          }
        }
      }
    }
  }
  // tail (E % 8 != 0) — first global thread; no-op at this problem size
  if (i == 0) {
    const int* er = (const int*)er4;
    const int* ec = (const int*)ec4;
    const float* ev = (const float*)ev4;
    for (int e = (E >> 3) << 3; e < E; ++e) {
      int r = er[e];
      if ((sbits[((unsigned)r) >> 5] >> (r & 31)) & 1u) {
        int p = atomicAdd(&counts[r], 1);
        if (p < CAPX) {
          unsigned pv = __float2uint_rn(ev[e] * VSCALE);
          lists[(size_t)r * CAPX + p] = (pv << 17) | (unsigned)ec[e];
        }
      }
    }
  }
}

// ---------------------------------------------------------------------------
// fused accumulate + build, v11 (R7 gather + B-wave prologue hoist):
//  * A-tasks: R7's proven loop (rounds=ceil(n/8), 2 x uint4 + 8 feat loads).
//  * B-tasks: the NEG gather's prologue (counts, 2x16B entry head, self row)
//    is issued BEFORE the POS loop, hiding its ~2-3 dependent L2/L3
//    latencies under the pos rounds. Unlike R8 (full interleave, register
//    blowup), this adds only ~13 VGPR. Arithmetic order bitwise identical.
//  * launch_bounds (256,4): R9 proved 8-vs-4 neutral; 4 avoids spill risk.
// ---------------------------------------------------------------------------
__global__ __launch_bounds__(256, 4) void accum_build_kernel(
    const int* __restrict__ counts, const unsigned* __restrict__ lists,
    const float* __restrict__ feat, const int* __restrict__ idx,
    const int* __restrict__ ipos, const int* __restrict__ ineg,
    unsigned short* __restrict__ A, unsigned short* __restrict__ Bm, int Bn) {
  int wv = (blockIdx.x * blockDim.x + threadIdx.x) >> 6;
  int lane = threadIdx.x & 63;

  // one 8-entry round: identical FP order to R7 (sa->acc0, sb->acc1)
  auto consume8 = [&](uint4 ea, uint4 eb, int j0, int n, float& acc0,
                      float& acc1) {
    unsigned sa[4] = {ea.x, ea.y, ea.z, ea.w};
    unsigned sb[4] = {eb.x, eb.y, eb.z, eb.w};
#pragma unroll
    for (int k = 0; k < 4; ++k) {
      unsigned e = (j0 + k < n) ? sa[k] : 0u;  // masked -> row 0 (L2-hot)
      float f = feat[((size_t)(e & 0x1FFFFu)) * DIM + lane];
      acc0 = fmaf((float)(e >> 17), f, acc0);
    }
#pragma unroll
    for (int k = 0; k < 4; ++k) {
      unsigned e = (j0 + 4 + k < n) ? sb[k] : 0u;
      float f = feat[((size_t)(e & 0x1FFFFu)) * DIM + lane];
      acc1 = fmaf((float)(e >> 17), f, acc1);
    }
  };

  auto gather = [&](int r) -> float {
    int n = counts[r];
    n = n > CAPX ? CAPX : n;
    const uint4* base4 = (const uint4*)(lists + (size_t)r * CAPX);
    float acc0 = 0.0f, acc1 = 0.0f;
    int rounds = (n + 7) >> 3;
    for (int c = 0; c < rounds; ++c)
      consume8(base4[2 * c], base4[2 * c + 1], c << 3, n, acc0, acc1);
    return 0.5f * ((acc0 + acc1) * VINV + feat[(size_t)r * DIM + lane]);
  };

  if (wv < Bn) {
    int b = wv;
    float v = gather(idx[b]);
    A[((size_t)((b >> 4) * 8 + (lane >> 3))) * 128 + (b & 15) * 8 + (lane & 7)] =
        f2bf(v);
  } else if (wv < 2 * Bn) {
    int j = wv - Bn;
    int rp = ipos[j];
    int rn = ineg[j];
    // ---- both prologues issued up front (neg's latency hides under pos) --
    int np = counts[rp];
    int nn = counts[rn];
    const uint4* bp = (const uint4*)(lists + (size_t)rp * CAPX);
    const uint4* bq = (const uint4*)(lists + (size_t)rn * CAPX);
    uint4 hp0 = bp[0], hp1 = bp[1];
    uint4 hq0 = bq[0], hq1 = bq[1];
    float selfp = feat[(size_t)rp * DIM + lane];
    float selfn = feat[(size_t)rn * DIM + lane];
    np = np > CAPX ? CAPX : np;
    nn = nn > CAPX ? CAPX : nn;
    // ---- pos loop (round 0 from preloaded head) -------------------------
    float p0 = 0.0f, p1 = 0.0f;
    int rpds = (np + 7) >> 3;
    if (rpds > 0) {
      consume8(hp0, hp1, 0, np, p0, p1);
      for (int c = 1; c < rpds; ++c)
        consume8(bp[2 * c], bp[2 * c + 1], c << 3, np, p0, p1);
    }
    // ---- neg loop (round 0 from preloaded head) -------------------------
    float q0 = 0.0f, q1 = 0.0f;
    int rnds = (nn + 7) >> 3;
    if (rnds > 0) {
      consume8(hq0, hq1, 0, nn, q0, q1);
      for (int c = 1; c < rnds; ++c)
        consume8(bq[2 * c], bq[2 * c + 1], c << 3, nn, q0, q1);
    }
    float v = 0.5f * ((p0 + p1) * VINV + selfp) -
              0.5f * ((q0 + q1) * VINV + selfn);
    Bm[((size_t)((j >> 4) * 8 + (lane >> 3))) * 128 + (j & 15) * 8 + (lane & 7)] =
        f2bf(v);
  }
}

// ---------------------------------------------------------------------------
// GEMM + loss via bf16 MFMA with fused, line-padded, sharded reduction
// (proven in R14). All-integer atomics -> deterministic.
// ---------------------------------------------------------------------------
__global__ __launch_bounds__(256) void gemm_loss_kernel(
    const short8* __restrict__ A, const short8* __restrict__ Bm,
    unsigned long long* __restrict__ sum_fixed, int* __restrict__ row_done,
    int* __restrict__ gdone, float* __restrict__ out, double inv) {
  int t = threadIdx.x;
  int lane = t & 63;
  int w = t >> 6;
  int wr = w >> 1;
  int wc = w & 1;
  int frow = lane & 15;
  int hi = lane >> 4;

  int ablk = blockIdx.y * 8 + wr * 4;
  int bblk = blockIdx.x * 8 + wc * 4;

  f32x4 acc[4][4];
#pragma unroll
  for (int m = 0; m < 4; ++m)
#pragma unroll
    for (int n = 0; n < 4; ++n) acc[m][n] = (f32x4){0.f, 0.f, 0.f, 0.f};

#pragma unroll
  for (int kk = 0; kk < 2; ++kk) {
    short8 a[4], b[4];
#pragma unroll
    for (int m = 0; m < 4; ++m)
      a[m] = A[((ablk + m) * 8 + kk * 4 + hi) * 16 + frow];
#pragma unroll
    for (int n = 0; n < 4; ++n)
      b[n] = Bm[((bblk + n) * 8 + kk * 4 + hi) * 16 + frow];
#pragma unroll
    for (int m = 0; m < 4; ++m)
#pragma unroll
      for (int n = 0; n < 4; ++n)
        acc[m][n] = __builtin_amdgcn_mfma_f32_16x16x32_bf16(a[m], b[n],
                                                            acc[m][n], 0, 0, 0);
  }

  float local = 0.0f;
#pragma unroll
  for (int m = 0; m < 4; ++m)
#pragma unroll
    for (int n = 0; n < 4; ++n)
#pragma unroll
      for (int i = 0; i < 4; ++i) {
        float z = -acc[m][n][i];
        float az = fabsf(z);
        local += fmaxf(z, 0.0f) + __logf(1.0f + __expf(-az));
      }
#pragma unroll
  for (int off = 32; off > 0; off >>= 1) local += __shfl_down(local, off, 64);

  __shared__ float red[4];
  if (lane == 0) red[w] = local;
  __syncthreads();

  if (w == 0) {
    int last = 0;
    if (lane == 0) {
      double bs = (double)red[0] + red[1] + red[2] + red[3];
      long long f = (long long)llrint(bs * 1048576.0);
      unsigned long long old =
          atomicAdd(&sum_fixed[blockIdx.y * SF_STRIDE], (unsigned long long)f);
      int inc = 1 | (int)(old >> 63);  // == 1, runtime-opaque (orders the add)
      int pos = atomicAdd(&row_done[blockIdx.y * RD_STRIDE], inc);
      if (pos == (int)gridDim.x - 1) {
        int g = atomicAdd(gdone, 1);
        last = (g == (int)gridDim.y - 1);
      }
    }
    last = __shfl(last, 0, 64);
    if (last) {
      long long part = 0;
      if (lane < (int)gridDim.y)
        part = (long long)atomicAdd(&sum_fixed[lane * SF_STRIDE], 0ULL);
#pragma unroll
      for (int off = 32; off > 0; off >>= 1)
        part += __shfl_down(part, off, 64);
      if (lane == 0)
        out[0] = (float)((double)part * inv * (1.0 / 1048576.0));
    }
  }
}

// ---------------------------------------------------------------------------
extern "C" void kernel_launch(void* const* d_in, const int* in_sizes, int n_in,
                              void* d_out, int out_size, void* d_ws,
                              size_t ws_size, hipStream_t stream) {
  const float* feat = (const float*)d_in[0];
  const float* evals = (const float*)d_in[1];
  const int* erows = (const int*)d_in[2];
  const int* ecols = (const int*)d_in[3];
  const int* idx = (const int*)d_in[4];
  const int* ipos = (const int*)d_in[5];
  const int* ineg = (const int*)d_in[6];
  float* out = (float*)d_out;

  int nItems = in_sizes[0] / DIM;
  int E = in_sizes[1];
  int Bn = in_sizes[4];

  // workspace bump allocator (256B aligned); ~53 MB of ~256 MiB ws.
  char* w = (char*)d_ws;
  size_t off = 0;
  auto alloc = [&](size_t bytes) -> void* {
    void* p = w + off;
    off += (bytes + 255) & ~(size_t)255;
    return p;
  };
  int* counts = (int*)alloc((size_t)nItems * 4);
  unsigned* lists = (unsigned*)alloc((size_t)nItems * CAPX * 4 + 2048);
  unsigned short* Amat = (unsigned short*)alloc((size_t)Bn * DIM * 2);
  unsigned short* Bmat = (unsigned short*)alloc((size_t)Bn * DIM * 2);
  int gx = Bn / 128;  // 32
  unsigned long long* sum_fixed =
      (unsigned long long*)alloc((size_t)gx * SF_STRIDE * 8);
  int* row_done = (int*)alloc((size_t)gx * RD_STRIDE * 4);
  int* gdone = (int*)alloc(64);

  prep_kernel<<<(3 * Bn + 255) / 256, 256, 0, stream>>>(
      idx, ipos, ineg, Bn, counts, sum_fixed, row_done, gdone, gx);

  int E8 = E / 8;
  scatter3_kernel<<<512, 1024, 0, stream>>>(
      (const int4*)erows, (const int4*)ecols, (const float4*)evals,
      (const int4*)idx, (const int4*)ipos, (const int4*)ineg, Bn / 4, counts,
      lists, E8, E);

  int nWaves = 2 * Bn;  // 4096 A-tasks + 4096 B-tasks
  accum_build_kernel<<<(nWaves * 64 + 255) / 256, 256, 0, stream>>>(
      counts, lists, feat, idx, ipos, ineg, Amat, Bmat, Bn);

  double inv = 1.0 / ((double)Bn * (double)Bn);
  gemm_loss_kernel<<<dim3(gx, gx), 256, 0, stream>>>(
      (const short8*)Amat, (const short8*)Bmat, sum_fixed, row_done, gdone,
      out, inv);
}